// Round 2
// baseline (52.005 us; speedup 1.0000x reference)
//
#include <hip/hip_runtime.h>
#include <stdint.h>

#define NFRAMES 2
#define NT 4           // NTYPES
#define BLK 256
#define NJ 16          // j-dimension split factor

// ---------------------------------------------------------------------------
// init: min_rr2 slots <- +inf bits, workspace counts <- 0
// ---------------------------------------------------------------------------
__global__ __launch_bounds__(BLK) void ns_init_kernel(unsigned* __restrict__ out_bits,
                                                      int ninf,
                                                      int* __restrict__ ws, int nws) {
    int idx = blockIdx.x * BLK + threadIdx.x;
    if (idx < ninf) out_bits[idx] = 0x7F800000u;  // +inf
    if (idx < nws)  ws[idx] = 0;
}

// ---------------------------------------------------------------------------
// pair kernel: each thread owns atom i, iterates a j-slice (wave-uniform j ->
// scalar loads). Bit-exact r2 vs numpy: contraction off, numpy reduce order.
// ---------------------------------------------------------------------------
__global__ __launch_bounds__(BLK) void ns_pair_kernel(const float* __restrict__ coord,
                                                      const int* __restrict__ atype,
                                                      unsigned* __restrict__ out_min_bits,
                                                      int* __restrict__ ws,
                                                      int nloc) {
#pragma clang fp contract(off)
    const int f = blockIdx.z;
    const int i = blockIdx.y * BLK + threadIdx.x;
    const int jslice = nloc / NJ;
    const int jbase = blockIdx.x * jslice;

    const float* cf = coord + (size_t)f * nloc * 3;
    const int*   tf = atype + (size_t)f * nloc;

    const float xi = cf[3 * i];
    const float yi = cf[3 * i + 1];
    const float zi = cf[3 * i + 2];

    float minr2 = __builtin_inff();
    int c0 = 0, c1 = 0, c2 = 0, c3 = 0;

#pragma unroll 8
    for (int j = jbase; j < jbase + jslice; ++j) {
        float dx = cf[3 * j]     - xi;
        float dy = cf[3 * j + 1] - yi;
        float dz = cf[3 * j + 2] - zi;
        int   tj = tf[j];
        // numpy order: (dx^2 + dy^2) + dz^2, no fma contraction
        float xx = dx * dx;
        float yy = dy * dy;
        float zz = dz * dz;
        float r2 = (xx + yy) + zz;
        bool self = (j == i);
        minr2 = fminf(minr2, self ? __builtin_inff() : r2);
        int nearby = (int)((r2 < 36.0f) & !self);
        c0 += nearby & (int)(tj == 0);
        c1 += nearby & (int)(tj == 1);
        c2 += nearby & (int)(tj == 2);
        c3 += nearby & (int)(tj == 3);
    }

    // merge partial min: float bits are order-preserving for non-negative values
    atomicMin(&out_min_bits[(size_t)f * nloc + i], __float_as_uint(minr2));
    int* w = ws + ((size_t)f * nloc + i) * NT;
    if (c0) atomicAdd(w + 0, c0);
    if (c1) atomicAdd(w + 1, c1);
    if (c2) atomicAdd(w + 2, c2);
    if (c3) atomicAdd(w + 3, c3);
}

// ---------------------------------------------------------------------------
// max over i per (frame, type); write as float (harness reads buffer as f32)
// ---------------------------------------------------------------------------
__global__ __launch_bounds__(BLK) void ns_max_kernel(const int* __restrict__ ws,
                                                     float* __restrict__ out,
                                                     int nloc) {
    const int f = blockIdx.x / NT;
    const int t = blockIdx.x % NT;
    int m = 0;
    for (int i = threadIdx.x; i < nloc; i += BLK)
        m = max(m, ws[((size_t)f * nloc + i) * NT + t]);
    // wave64 butterfly reduce
    for (int off = 32; off > 0; off >>= 1)
        m = max(m, __shfl_xor(m, off, 64));
    __shared__ int red[BLK / 64];
    int wid = threadIdx.x >> 6;
    if ((threadIdx.x & 63) == 0) red[wid] = m;
    __syncthreads();
    if (threadIdx.x == 0) {
        m = max(max(red[0], red[1]), max(red[2], red[3]));
        out[(size_t)NFRAMES * nloc + f * NT + t] = (float)m;
    }
}

extern "C" void kernel_launch(void* const* d_in, const int* in_sizes, int n_in,
                              void* d_out, int out_size, void* d_ws, size_t ws_size,
                              hipStream_t stream) {
    const float* coord = (const float*)d_in[0];
    const int*   atype = (const int*)d_in[1];
    const int nloc = in_sizes[1] / NFRAMES;

    float* out = (float*)d_out;
    int*   ws  = (int*)d_ws;

    const int ninf = NFRAMES * nloc;            // min_rr2 element count
    const int nws  = NFRAMES * nloc * NT;       // per-(i,t) counters
    const int initn = (ninf > nws) ? ninf : nws;

    ns_init_kernel<<<(initn + BLK - 1) / BLK, BLK, 0, stream>>>(
        (unsigned*)out, ninf, ws, nws);

    dim3 grid(NJ, nloc / BLK, NFRAMES);
    ns_pair_kernel<<<grid, dim3(BLK), 0, stream>>>(
        coord, atype, (unsigned*)out, ws, nloc);

    ns_max_kernel<<<NFRAMES * NT, BLK, 0, stream>>>(ws, out, nloc);
}

// Round 3
// 27.560 us; speedup vs baseline: 1.8870x; 1.8870x over previous
//
#include <hip/hip_runtime.h>
#include <stdint.h>

#define NFRAMES 2
#define NT 4           // NTYPES
#define BLK 256
#define NJ 64          // j-dimension split factor (jslice = nloc/NJ = 64)

// ---------------------------------------------------------------------------
// init: min_rr2 slots <- +inf bits, packed-count workspace <- 0
// ---------------------------------------------------------------------------
__global__ __launch_bounds__(BLK) void ns_init_kernel(unsigned* __restrict__ out_bits,
                                                      unsigned* __restrict__ ws, int n) {
    int idx = blockIdx.x * BLK + threadIdx.x;
    if (idx < n) {
        out_bits[idx] = 0x7F800000u;  // +inf
        ws[idx] = 0u;
    }
}

// ---------------------------------------------------------------------------
// one pair interaction; bit-exact r2 vs numpy ((dx^2+dy^2)+dz^2, no contract)
// ---------------------------------------------------------------------------
template <bool SELFCHK>
__device__ __forceinline__ void do_pair(const float* __restrict__ cf,
                                        const int* __restrict__ tf,
                                        int j, int i,
                                        float xi, float yi, float zi,
                                        float& mm, unsigned& cc) {
#pragma clang fp contract(off)
    float dx = cf[3 * j]     - xi;
    float dy = cf[3 * j + 1] - yi;
    float dz = cf[3 * j + 2] - zi;
    unsigned sval = 1u << (tf[j] * 8);   // wave-uniform -> SALU
    float xx = dx * dx;
    float yy = dy * dy;
    float zz = dz * dz;
    float r2 = (xx + yy) + zz;
    bool self = SELFCHK && (j == i);
    float rm = self ? __builtin_inff() : r2;
    mm = fminf(mm, rm);
    bool near = (r2 < 36.0f) && !self;
    cc += near ? sval : 0u;
}

// ---------------------------------------------------------------------------
// pair kernel: thread owns atom i; iterates a 64-long j-slice (wave-uniform j
// -> scalar loads). Packed per-type counts, 2 atomics per thread.
// ---------------------------------------------------------------------------
__global__ __launch_bounds__(BLK) void ns_pair_kernel(const float* __restrict__ coord,
                                                      const int* __restrict__ atype,
                                                      unsigned* __restrict__ out_min_bits,
                                                      unsigned* __restrict__ ws_cnt,
                                                      int nloc) {
    const int f = blockIdx.z;
    const int ibase = blockIdx.y * BLK;
    const int i = ibase + threadIdx.x;
    const int jslice = nloc / NJ;
    const int jbase = blockIdx.x * jslice;

    const float* cf = coord + (size_t)f * nloc * 3;
    const int*   tf = atype + (size_t)f * nloc;

    const float xi = cf[3 * i];
    const float yi = cf[3 * i + 1];
    const float zi = cf[3 * i + 2];

    float m0 = __builtin_inff(), m1 = __builtin_inff();
    unsigned c0 = 0u, c1 = 0u;

    // block-uniform: does this j-chunk contain any thread's self pair?
    const bool overlap = (jbase >= ibase) && (jbase < ibase + BLK);

    if (overlap) {
#pragma unroll 8
        for (int j = jbase; j < jbase + jslice; j += 2) {
            do_pair<true>(cf, tf, j,     i, xi, yi, zi, m0, c0);
            do_pair<true>(cf, tf, j + 1, i, xi, yi, zi, m1, c1);
        }
    } else {
#pragma unroll 8
        for (int j = jbase; j < jbase + jslice; j += 2) {
            do_pair<false>(cf, tf, j,     i, xi, yi, zi, m0, c0);
            do_pair<false>(cf, tf, j + 1, i, xi, yi, zi, m1, c1);
        }
    }

    float minr2 = fminf(m0, m1);
    unsigned c = c0 + c1;

    // float bits order-preserving for non-negative values
    atomicMin(&out_min_bits[(size_t)f * nloc + i], __float_as_uint(minr2));
    atomicAdd(&ws_cnt[(size_t)f * nloc + i], c);
}

// ---------------------------------------------------------------------------
// per-frame max over i of packed per-type counts; write as float
// ---------------------------------------------------------------------------
__global__ __launch_bounds__(BLK) void ns_max_kernel(const unsigned* __restrict__ ws_cnt,
                                                     float* __restrict__ out,
                                                     int nloc) {
    const int f = blockIdx.x;
    int m0 = 0, m1 = 0, m2 = 0, m3 = 0;
    for (int i = threadIdx.x; i < nloc; i += BLK) {
        unsigned c = ws_cnt[(size_t)f * nloc + i];
        m0 = max(m0, (int)(c & 255u));
        m1 = max(m1, (int)((c >> 8) & 255u));
        m2 = max(m2, (int)((c >> 16) & 255u));
        m3 = max(m3, (int)(c >> 24));
    }
    for (int off = 32; off > 0; off >>= 1) {
        m0 = max(m0, __shfl_xor(m0, off, 64));
        m1 = max(m1, __shfl_xor(m1, off, 64));
        m2 = max(m2, __shfl_xor(m2, off, 64));
        m3 = max(m3, __shfl_xor(m3, off, 64));
    }
    __shared__ int red[BLK / 64][NT];
    int wid = threadIdx.x >> 6;
    if ((threadIdx.x & 63) == 0) {
        red[wid][0] = m0; red[wid][1] = m1; red[wid][2] = m2; red[wid][3] = m3;
    }
    __syncthreads();
    if (threadIdx.x < NT) {
        int t = threadIdx.x;
        int m = max(max(red[0][t], red[1][t]), max(red[2][t], red[3][t]));
        out[(size_t)NFRAMES * nloc + f * NT + t] = (float)m;
    }
}

extern "C" void kernel_launch(void* const* d_in, const int* in_sizes, int n_in,
                              void* d_out, int out_size, void* d_ws, size_t ws_size,
                              hipStream_t stream) {
    const float* coord = (const float*)d_in[0];
    const int*   atype = (const int*)d_in[1];
    const int nloc = in_sizes[1] / NFRAMES;

    float*    out = (float*)d_out;
    unsigned* ws  = (unsigned*)d_ws;

    const int n = NFRAMES * nloc;   // min slots == packed-count slots

    ns_init_kernel<<<(n + BLK - 1) / BLK, BLK, 0, stream>>>((unsigned*)out, ws, n);

    dim3 grid(NJ, nloc / BLK, NFRAMES);
    ns_pair_kernel<<<grid, dim3(BLK), 0, stream>>>(coord, atype, (unsigned*)out, ws, nloc);

    ns_max_kernel<<<NFRAMES, BLK, 0, stream>>>(ws, out, nloc);
}

// Round 4
// 27.512 us; speedup vs baseline: 1.8903x; 1.0018x over previous
//
#include <hip/hip_runtime.h>
#include <stdint.h>

#define NFRAMES 2
#define NT 4           // NTYPES
#define BLK 256
#define NJ 64          // j-dimension split factor (jslice = nloc/NJ = 64)

// ---------------------------------------------------------------------------
// one pair interaction; bit-exact r2 vs numpy ((dx^2+dy^2)+dz^2, no contract)
// ---------------------------------------------------------------------------
template <bool SELFCHK>
__device__ __forceinline__ void do_pair(const float* __restrict__ cf,
                                        const int* __restrict__ tf,
                                        int j, int i,
                                        float xi, float yi, float zi,
                                        float& mm, unsigned& cc) {
#pragma clang fp contract(off)
    float dx = cf[3 * j]     - xi;
    float dy = cf[3 * j + 1] - yi;
    float dz = cf[3 * j + 2] - zi;
    unsigned sval = 1u << (tf[j] * 8);   // wave-uniform -> SALU
    float xx = dx * dx;
    float yy = dy * dy;
    float zz = dz * dz;
    float r2 = (xx + yy) + zz;
    bool self = SELFCHK && (j == i);
    float rm = self ? __builtin_inff() : r2;
    mm = fminf(mm, rm);
    bool near = (r2 < 36.0f) && !self;
    cc += near ? sval : 0u;
}

// ---------------------------------------------------------------------------
// pair kernel: thread owns atom i; iterates a 64-long j-slice (wave-uniform j
// -> scalar loads). Writes partial {min_bits, packed_cnt} -- NO atomics.
// ---------------------------------------------------------------------------
__global__ __launch_bounds__(BLK) void ns_pair_kernel(const float* __restrict__ coord,
                                                      const int* __restrict__ atype,
                                                      uint2* __restrict__ part,
                                                      int nloc) {
    const int f = blockIdx.z;
    const int ibase = blockIdx.y * BLK;
    const int i = ibase + threadIdx.x;
    const int jslice = nloc / NJ;
    const int jb = blockIdx.x;
    const int jbase = jb * jslice;

    const float* cf = coord + (size_t)f * nloc * 3;
    const int*   tf = atype + (size_t)f * nloc;

    const float xi = cf[3 * i];
    const float yi = cf[3 * i + 1];
    const float zi = cf[3 * i + 2];

    float m0 = __builtin_inff(), m1 = __builtin_inff();
    unsigned c0 = 0u, c1 = 0u;

    // block-uniform: does this j-chunk contain any thread's self pair?
    const bool overlap = (jbase >= ibase) && (jbase < ibase + BLK);

    if (overlap) {
#pragma unroll 8
        for (int j = jbase; j < jbase + jslice; j += 2) {
            do_pair<true>(cf, tf, j,     i, xi, yi, zi, m0, c0);
            do_pair<true>(cf, tf, j + 1, i, xi, yi, zi, m1, c1);
        }
    } else {
#pragma unroll 8
        for (int j = jbase; j < jbase + jslice; j += 2) {
            do_pair<false>(cf, tf, j,     i, xi, yi, zi, m0, c0);
            do_pair<false>(cf, tf, j + 1, i, xi, yi, zi, m1, c1);
        }
    }

    float minr2 = fminf(m0, m1);
    unsigned c = c0 + c1;

    part[((size_t)jb * NFRAMES + f) * nloc + i] =
        make_uint2(__float_as_uint(minr2), c);
}

// ---------------------------------------------------------------------------
// finalize: per (f,i) reduce the NJ partials; write min_rr2 to out, and
// per-block per-type count maxes to pmax (no atomics anywhere).
// ---------------------------------------------------------------------------
__global__ __launch_bounds__(BLK) void ns_finalize_kernel(const uint2* __restrict__ part,
                                                          float* __restrict__ out,
                                                          int* __restrict__ pmax,
                                                          int nloc) {
    const int nbpf = nloc / BLK;                 // blocks per frame (16)
    const int f  = blockIdx.x / nbpf;
    const int ib = blockIdx.x % nbpf;
    const int i  = ib * BLK + threadIdx.x;

    float m = __builtin_inff();
    unsigned c = 0u;
#pragma unroll 16
    for (int jb = 0; jb < NJ; ++jb) {
        uint2 v = part[((size_t)jb * NFRAMES + f) * nloc + i];
        m = fminf(m, __uint_as_float(v.x));
        c += v.y;
    }
    out[(size_t)f * nloc + i] = m;

    int m0 = (int)(c & 255u);
    int m1 = (int)((c >> 8) & 255u);
    int m2 = (int)((c >> 16) & 255u);
    int m3 = (int)(c >> 24);
    for (int off = 32; off > 0; off >>= 1) {
        m0 = max(m0, __shfl_xor(m0, off, 64));
        m1 = max(m1, __shfl_xor(m1, off, 64));
        m2 = max(m2, __shfl_xor(m2, off, 64));
        m3 = max(m3, __shfl_xor(m3, off, 64));
    }
    __shared__ int red[BLK / 64][NT];
    int wid = threadIdx.x >> 6;
    if ((threadIdx.x & 63) == 0) {
        red[wid][0] = m0; red[wid][1] = m1; red[wid][2] = m2; red[wid][3] = m3;
    }
    __syncthreads();
    if (threadIdx.x < NT) {
        int t = threadIdx.x;
        pmax[blockIdx.x * NT + t] =
            max(max(red[0][t], red[1][t]), max(red[2][t], red[3][t]));
    }
}

// ---------------------------------------------------------------------------
// tail: fold the per-block partial maxes into the 8 output scalars
// ---------------------------------------------------------------------------
__global__ __launch_bounds__(64) void ns_max_kernel(const int* __restrict__ pmax,
                                                    float* __restrict__ out,
                                                    int nbpf, int nloc) {
    const int t = threadIdx.x;
    if (t < NFRAMES * NT) {
        const int f = t / NT, tt = t % NT;
        int m = 0;
        for (int b = 0; b < nbpf; ++b)
            m = max(m, pmax[(f * nbpf + b) * NT + tt]);
        out[(size_t)NFRAMES * nloc + f * NT + tt] = (float)m;
    }
}

extern "C" void kernel_launch(void* const* d_in, const int* in_sizes, int n_in,
                              void* d_out, int out_size, void* d_ws, size_t ws_size,
                              hipStream_t stream) {
    const float* coord = (const float*)d_in[0];
    const int*   atype = (const int*)d_in[1];
    const int nloc = in_sizes[1] / NFRAMES;

    float* out = (float*)d_out;
    uint2* part = (uint2*)d_ws;                                  // NJ*F*nloc uint2
    int*   pmax = (int*)((char*)d_ws + (size_t)NJ * NFRAMES * nloc * sizeof(uint2));

    dim3 grid(NJ, nloc / BLK, NFRAMES);
    ns_pair_kernel<<<grid, dim3(BLK), 0, stream>>>(coord, atype, part, nloc);

    const int nbpf = nloc / BLK;
    ns_finalize_kernel<<<NFRAMES * nbpf, BLK, 0, stream>>>(part, out, pmax, nloc);

    ns_max_kernel<<<1, 64, 0, stream>>>(pmax, out, nbpf, nloc);
}

// Round 5
// 27.275 us; speedup vs baseline: 1.9066x; 1.0087x over previous
//
#include <hip/hip_runtime.h>
#include <stdint.h>

#define NFRAMES 2
#define NT 4           // NTYPES
#define BLK 256
#define NJ 128         // j-dimension split (jslice = nloc/NJ = 32)
// each thread owns atoms i and i + nloc/2 (IPT=2)

// ---------------------------------------------------------------------------
// one pair interaction; bit-exact r2 vs numpy ((dx^2+dy^2)+dz^2, no contract)
// ---------------------------------------------------------------------------
template <bool SELFCHK>
__device__ __forceinline__ void do_pair(float cx, float cy, float cz, unsigned sval,
                                        int j, int i,
                                        float xi, float yi, float zi,
                                        float& mm, unsigned& cc) {
#pragma clang fp contract(off)
    float dx = cx - xi;
    float dy = cy - yi;
    float dz = cz - zi;
    float xx = dx * dx;
    float yy = dy * dy;
    float zz = dz * dz;
    float r2 = (xx + yy) + zz;
    bool self = SELFCHK && (j == i);
    float rm = self ? __builtin_inff() : r2;
    mm = fminf(mm, rm);
    bool near = (r2 < 36.0f) && !self;
    cc += near ? sval : 0u;
}

// ---------------------------------------------------------------------------
// pair kernel: thread owns atoms i1 = ibase+tid and i2 = i1 + nloc/2; each
// wave-uniform j load (scalar) feeds BOTH atoms -> 2x ILP per stall window.
// Writes partial {min_bits, packed_cnt} per atom -- no atomics, no init.
// ---------------------------------------------------------------------------
__global__ __launch_bounds__(BLK) void ns_pair_kernel(const float* __restrict__ coord,
                                                      const int* __restrict__ atype,
                                                      uint2* __restrict__ part,
                                                      int nloc) {
    const int f = blockIdx.z;
    const int half = nloc >> 1;
    const int ibase1 = blockIdx.y * BLK;          // in [0, half)
    const int ibase2 = ibase1 + half;
    const int i1 = ibase1 + threadIdx.x;
    const int i2 = ibase2 + threadIdx.x;
    const int jslice = nloc / NJ;                 // 32
    const int jb = blockIdx.x;
    const int jbase = jb * jslice;

    const float* cf = coord + (size_t)f * nloc * 3;
    const int*   tf = atype + (size_t)f * nloc;

    const float x1 = cf[3 * i1], y1 = cf[3 * i1 + 1], z1 = cf[3 * i1 + 2];
    const float x2 = cf[3 * i2], y2 = cf[3 * i2 + 1], z2 = cf[3 * i2 + 2];

    float m1a = __builtin_inff(), m1b = __builtin_inff();
    float m2a = __builtin_inff(), m2b = __builtin_inff();
    unsigned c1a = 0u, c1b = 0u, c2a = 0u, c2b = 0u;

    // jslice (32, aligned) sits entirely inside one 256-aligned i-range:
    const bool overlap = (jbase >= ibase1 && jbase < ibase1 + BLK) ||
                         (jbase >= ibase2 && jbase < ibase2 + BLK);

    if (overlap) {
#pragma unroll 4
        for (int j = jbase; j < jbase + jslice; j += 2) {
            float cx0 = cf[3 * j],     cy0 = cf[3 * j + 1], cz0 = cf[3 * j + 2];
            unsigned s0 = 1u << (tf[j] * 8);
            do_pair<true>(cx0, cy0, cz0, s0, j, i1, x1, y1, z1, m1a, c1a);
            do_pair<true>(cx0, cy0, cz0, s0, j, i2, x2, y2, z2, m2a, c2a);
            float cx1 = cf[3 * j + 3], cy1 = cf[3 * j + 4], cz1 = cf[3 * j + 5];
            unsigned s1 = 1u << (tf[j + 1] * 8);
            do_pair<true>(cx1, cy1, cz1, s1, j + 1, i1, x1, y1, z1, m1b, c1b);
            do_pair<true>(cx1, cy1, cz1, s1, j + 1, i2, x2, y2, z2, m2b, c2b);
        }
    } else {
#pragma unroll 4
        for (int j = jbase; j < jbase + jslice; j += 2) {
            float cx0 = cf[3 * j],     cy0 = cf[3 * j + 1], cz0 = cf[3 * j + 2];
            unsigned s0 = 1u << (tf[j] * 8);
            do_pair<false>(cx0, cy0, cz0, s0, j, i1, x1, y1, z1, m1a, c1a);
            do_pair<false>(cx0, cy0, cz0, s0, j, i2, x2, y2, z2, m2a, c2a);
            float cx1 = cf[3 * j + 3], cy1 = cf[3 * j + 4], cz1 = cf[3 * j + 5];
            unsigned s1 = 1u << (tf[j + 1] * 8);
            do_pair<false>(cx1, cy1, cz1, s1, j + 1, i1, x1, y1, z1, m1b, c1b);
            do_pair<false>(cx1, cy1, cz1, s1, j + 1, i2, x2, y2, z2, m2b, c2b);
        }
    }

    const size_t base = ((size_t)jb * NFRAMES + f) * nloc;
    part[base + i1] = make_uint2(__float_as_uint(fminf(m1a, m1b)), c1a + c1b);
    part[base + i2] = make_uint2(__float_as_uint(fminf(m2a, m2b)), c2a + c2b);
}

// ---------------------------------------------------------------------------
// finalize: per (f,i) reduce the NJ partials; write min_rr2 to out, and
// per-block per-type count maxes to pmax (no atomics anywhere).
// ---------------------------------------------------------------------------
__global__ __launch_bounds__(BLK) void ns_finalize_kernel(const uint2* __restrict__ part,
                                                          float* __restrict__ out,
                                                          int* __restrict__ pmax,
                                                          int nloc) {
    const int nbpf = nloc / BLK;                 // blocks per frame (16)
    const int f  = blockIdx.x / nbpf;
    const int ib = blockIdx.x % nbpf;
    const int i  = ib * BLK + threadIdx.x;

    float ma = __builtin_inff(), mb = __builtin_inff();
    unsigned ca = 0u, cb = 0u;
#pragma unroll 8
    for (int jb = 0; jb < NJ; jb += 2) {
        uint2 va = part[((size_t)jb * NFRAMES + f) * nloc + i];
        uint2 vb = part[((size_t)(jb + 1) * NFRAMES + f) * nloc + i];
        ma = fminf(ma, __uint_as_float(va.x));
        mb = fminf(mb, __uint_as_float(vb.x));
        ca += va.y;
        cb += vb.y;
    }
    out[(size_t)f * nloc + i] = fminf(ma, mb);
    unsigned c = ca + cb;

    int m0 = (int)(c & 255u);
    int m1 = (int)((c >> 8) & 255u);
    int m2 = (int)((c >> 16) & 255u);
    int m3 = (int)(c >> 24);
    for (int off = 32; off > 0; off >>= 1) {
        m0 = max(m0, __shfl_xor(m0, off, 64));
        m1 = max(m1, __shfl_xor(m1, off, 64));
        m2 = max(m2, __shfl_xor(m2, off, 64));
        m3 = max(m3, __shfl_xor(m3, off, 64));
    }
    __shared__ int red[BLK / 64][NT];
    int wid = threadIdx.x >> 6;
    if ((threadIdx.x & 63) == 0) {
        red[wid][0] = m0; red[wid][1] = m1; red[wid][2] = m2; red[wid][3] = m3;
    }
    __syncthreads();
    if (threadIdx.x < NT) {
        int t = threadIdx.x;
        pmax[blockIdx.x * NT + t] =
            max(max(red[0][t], red[1][t]), max(red[2][t], red[3][t]));
    }
}

// ---------------------------------------------------------------------------
// tail: fold the per-block partial maxes into the 8 output scalars
// ---------------------------------------------------------------------------
__global__ __launch_bounds__(64) void ns_max_kernel(const int* __restrict__ pmax,
                                                    float* __restrict__ out,
                                                    int nbpf, int nloc) {
    const int t = threadIdx.x;
    if (t < NFRAMES * NT) {
        const int f = t / NT, tt = t % NT;
        int m = 0;
        for (int b = 0; b < nbpf; ++b)
            m = max(m, pmax[(f * nbpf + b) * NT + tt]);
        out[(size_t)NFRAMES * nloc + f * NT + tt] = (float)m;
    }
}

extern "C" void kernel_launch(void* const* d_in, const int* in_sizes, int n_in,
                              void* d_out, int out_size, void* d_ws, size_t ws_size,
                              hipStream_t stream) {
    const float* coord = (const float*)d_in[0];
    const int*   atype = (const int*)d_in[1];
    const int nloc = in_sizes[1] / NFRAMES;

    float* out = (float*)d_out;
    uint2* part = (uint2*)d_ws;                                  // NJ*F*nloc uint2
    int*   pmax = (int*)((char*)d_ws + (size_t)NJ * NFRAMES * nloc * sizeof(uint2));

    dim3 grid(NJ, nloc / (BLK * 2), NFRAMES);
    ns_pair_kernel<<<grid, dim3(BLK), 0, stream>>>(coord, atype, part, nloc);

    const int nbpf = nloc / BLK;
    ns_finalize_kernel<<<NFRAMES * nbpf, BLK, 0, stream>>>(part, out, pmax, nloc);

    ns_max_kernel<<<1, 64, 0, stream>>>(pmax, out, nbpf, nloc);
}

// Round 6
// 26.525 us; speedup vs baseline: 1.9606x; 1.0283x over previous
//
#include <hip/hip_runtime.h>
#include <stdint.h>

#define NFRAMES 2
#define NT 4           // NTYPES
#define BLK 256        // pair-kernel block size
#define NJ 128         // j-dimension split (jslice = nloc/NJ = 32)
#define IPT 4          // atoms per thread in pair kernel
#define FBLK 128       // finalize block size

// ---------------------------------------------------------------------------
// one pair interaction; bit-exact r2 vs numpy ((dx^2+dy^2)+dz^2, no contract)
// ---------------------------------------------------------------------------
template <bool SELFCHK>
__device__ __forceinline__ void do_pair(float cx, float cy, float cz, unsigned sval,
                                        int j, int i,
                                        float xi, float yi, float zi,
                                        float& mm, unsigned& cc) {
#pragma clang fp contract(off)
    float dx = cx - xi;
    float dy = cy - yi;
    float dz = cz - zi;
    float xx = dx * dx;
    float yy = dy * dy;
    float zz = dz * dz;
    float r2 = (xx + yy) + zz;
    bool self = SELFCHK && (j == i);
    mm = fminf(mm, self ? __builtin_inff() : r2);
    bool near = (r2 < 36.0f) && !self;
    cc += near ? sval : 0u;
}

// ---------------------------------------------------------------------------
// inner j-loop over one slice; every scalar j-load feeds IPT atoms (4x ILP)
// ---------------------------------------------------------------------------
template <bool SELFCHK>
__device__ __forceinline__ void pair_body(const float* __restrict__ cf,
                                          const int* __restrict__ tf,
                                          int jbase, int jslice,
                                          const int (&ii)[IPT],
                                          const float (&xi)[IPT],
                                          const float (&yi)[IPT],
                                          const float (&zi)[IPT],
                                          float (&ma)[IPT], float (&mb)[IPT],
                                          unsigned (&ca)[IPT], unsigned (&cb)[IPT]) {
#pragma unroll 4
    for (int j = jbase; j < jbase + jslice; j += 2) {
        float cx0 = cf[3 * j], cy0 = cf[3 * j + 1], cz0 = cf[3 * j + 2];
        unsigned s0 = 1u << (tf[j] * 8);          // wave-uniform -> SALU
#pragma unroll
        for (int k = 0; k < IPT; ++k)
            do_pair<SELFCHK>(cx0, cy0, cz0, s0, j, ii[k], xi[k], yi[k], zi[k], ma[k], ca[k]);
        float cx1 = cf[3 * j + 3], cy1 = cf[3 * j + 4], cz1 = cf[3 * j + 5];
        unsigned s1 = 1u << (tf[j + 1] * 8);
#pragma unroll
        for (int k = 0; k < IPT; ++k)
            do_pair<SELFCHK>(cx1, cy1, cz1, s1, j + 1, ii[k], xi[k], yi[k], zi[k], mb[k], cb[k]);
    }
}

// ---------------------------------------------------------------------------
// pair kernel: thread owns IPT=4 atoms; writes partial {min_bits, packed_cnt}
// per atom. Also zeroes the 8 output tail slots (block 0) for the atomicMax
// in the finalize kernel.
// ---------------------------------------------------------------------------
__global__ __launch_bounds__(BLK) void ns_pair_kernel(const float* __restrict__ coord,
                                                      const int* __restrict__ atype,
                                                      uint2* __restrict__ part,
                                                      float* __restrict__ out,
                                                      int nloc) {
    const int f = blockIdx.z;
    const int q = nloc >> 2;                      // 1024
    const int ib = blockIdx.y * BLK;              // in [0, q)
    const int jslice = nloc / NJ;                 // 32
    const int jb = blockIdx.x;
    const int jbase = jb * jslice;

    if (blockIdx.x == 0 && blockIdx.y == 0 && blockIdx.z == 0 &&
        threadIdx.x < NFRAMES * NT)
        ((unsigned*)out)[(size_t)NFRAMES * nloc + threadIdx.x] = 0u;  // 0.0f bits

    const float* cf = coord + (size_t)f * nloc * 3;
    const int*   tf = atype + (size_t)f * nloc;

    int ii[IPT];
    float xi[IPT], yi[IPT], zi[IPT];
    float ma[IPT], mb[IPT];
    unsigned ca[IPT], cb[IPT];
    bool ov = false;
#pragma unroll
    for (int k = 0; k < IPT; ++k) {
        const int base = ib + k * q;
        ii[k] = base + threadIdx.x;
        xi[k] = cf[3 * ii[k]];
        yi[k] = cf[3 * ii[k] + 1];
        zi[k] = cf[3 * ii[k] + 2];
        ma[k] = mb[k] = __builtin_inff();
        ca[k] = cb[k] = 0u;
        ov |= (jbase >= base) && (jbase < base + BLK);
    }

    if (ov)
        pair_body<true >(cf, tf, jbase, jslice, ii, xi, yi, zi, ma, mb, ca, cb);
    else
        pair_body<false>(cf, tf, jbase, jslice, ii, xi, yi, zi, ma, mb, ca, cb);

    const size_t pb = ((size_t)jb * NFRAMES + f) * nloc;
#pragma unroll
    for (int k = 0; k < IPT; ++k)
        part[pb + ii[k]] = make_uint2(__float_as_uint(fminf(ma[k], mb[k])), ca[k] + cb[k]);
}

// ---------------------------------------------------------------------------
// finalize: per (f,i) reduce the NJ partials; write min_rr2 to out; fold
// per-type count maxes straight into out tail via atomicMax on float bits
// (monotone for non-negative values). No third kernel.
// ---------------------------------------------------------------------------
__global__ __launch_bounds__(FBLK) void ns_finalize_kernel(const uint2* __restrict__ part,
                                                           float* __restrict__ out,
                                                           int nloc) {
    const int nbpf = nloc / FBLK;                 // 32 blocks per frame
    const int f = blockIdx.x / nbpf;
    const int i = (blockIdx.x % nbpf) * FBLK + threadIdx.x;

    float ma = __builtin_inff(), mb = __builtin_inff();
    unsigned cacc = 0u, cbacc = 0u;
#pragma unroll 8
    for (int jb = 0; jb < NJ; jb += 2) {
        uint2 va = part[((size_t)jb * NFRAMES + f) * nloc + i];
        uint2 vb = part[((size_t)(jb + 1) * NFRAMES + f) * nloc + i];
        ma = fminf(ma, __uint_as_float(va.x));
        mb = fminf(mb, __uint_as_float(vb.x));
        cacc += va.y;
        cbacc += vb.y;
    }
    out[(size_t)f * nloc + i] = fminf(ma, mb);
    const unsigned c = cacc + cbacc;

    int m0 = (int)(c & 255u);
    int m1 = (int)((c >> 8) & 255u);
    int m2 = (int)((c >> 16) & 255u);
    int m3 = (int)(c >> 24);
    for (int off = 32; off > 0; off >>= 1) {
        m0 = max(m0, __shfl_xor(m0, off, 64));
        m1 = max(m1, __shfl_xor(m1, off, 64));
        m2 = max(m2, __shfl_xor(m2, off, 64));
        m3 = max(m3, __shfl_xor(m3, off, 64));
    }
    __shared__ int red[FBLK / 64][NT];
    const int wid = threadIdx.x >> 6;
    if ((threadIdx.x & 63) == 0) {
        red[wid][0] = m0; red[wid][1] = m1; red[wid][2] = m2; red[wid][3] = m3;
    }
    __syncthreads();
    if (threadIdx.x < NT) {
        const int t = threadIdx.x;
        const int m = max(red[0][t], red[1][t]);
        atomicMax((unsigned*)out + (size_t)NFRAMES * nloc + f * NT + t,
                  __float_as_uint((float)m));
    }
}

extern "C" void kernel_launch(void* const* d_in, const int* in_sizes, int n_in,
                              void* d_out, int out_size, void* d_ws, size_t ws_size,
                              hipStream_t stream) {
    const float* coord = (const float*)d_in[0];
    const int*   atype = (const int*)d_in[1];
    const int nloc = in_sizes[1] / NFRAMES;

    float* out  = (float*)d_out;
    uint2* part = (uint2*)d_ws;                   // NJ * NFRAMES * nloc uint2

    dim3 grid(NJ, nloc / (BLK * IPT), NFRAMES);
    ns_pair_kernel<<<grid, dim3(BLK), 0, stream>>>(coord, atype, part, out, nloc);

    const int nbpf = nloc / FBLK;
    ns_finalize_kernel<<<NFRAMES * nbpf, FBLK, 0, stream>>>(part, out, nloc);
}

// Round 7
// 24.212 us; speedup vs baseline: 2.1478x; 1.0955x over previous
//
#include <hip/hip_runtime.h>
#include <stdint.h>

#define NFRAMES 2
#define NT 4           // NTYPES
#define BLK 256        // pair-kernel block size (4 waves)
#define NJ 64          // j-split: jslice = nloc/NJ = 64 = one wave-chunk
#define IPT 4          // atoms per thread in pair kernel
#define FBLK 128       // finalize block size

// broadcast lane l's float across the wave via readlane (pure VALU, exact bits)
__device__ __forceinline__ float bcast_f(float v, int l) {
    return __uint_as_float(__builtin_amdgcn_readlane(__float_as_uint(v), l));
}

// ---------------------------------------------------------------------------
// one pair interaction; bit-exact r2 vs numpy ((dx^2+dy^2)+dz^2, no contract)
// cx,cy,cz,sval are wave-uniform (SGPR) j-atom data.
// ---------------------------------------------------------------------------
template <bool SELFCHK>
__device__ __forceinline__ void do_pair(float cx, float cy, float cz, unsigned sval,
                                        int j, int i,
                                        float xi, float yi, float zi,
                                        float& mm, unsigned& cc) {
#pragma clang fp contract(off)
    float dx = cx - xi;
    float dy = cy - yi;
    float dz = cz - zi;
    float xx = dx * dx;
    float yy = dy * dy;
    float zz = dz * dz;
    float r2 = (xx + yy) + zz;
    bool self = SELFCHK && (j == i);
    mm = fminf(mm, self ? __builtin_inff() : r2);
    bool near = (r2 < 36.0f) && !self;
    cc += near ? sval : 0u;
}

// ---------------------------------------------------------------------------
// inner loop over a 64-atom chunk held in per-lane regs (bx,by,bz,bs):
// zero memory ops -- 4 readlanes + IPT*11 VALU per j. Two accumulator banks
// (even/odd l) give 8 independent chains per thread.
// ---------------------------------------------------------------------------
template <bool SELFCHK>
__device__ __forceinline__ void chunk_loop(float bx, float by, float bz, unsigned bs,
                                           int jbase,
                                           const int (&ii)[IPT],
                                           const float (&xi)[IPT],
                                           const float (&yi)[IPT],
                                           const float (&zi)[IPT],
                                           float (&mA)[IPT], float (&mB)[IPT],
                                           unsigned (&cA)[IPT], unsigned (&cB)[IPT]) {
#pragma unroll 8
    for (int l = 0; l < 64; l += 2) {
        float cx0 = bcast_f(bx, l), cy0 = bcast_f(by, l), cz0 = bcast_f(bz, l);
        unsigned s0 = __builtin_amdgcn_readlane(bs, l);
        const int j0 = jbase + l;
#pragma unroll
        for (int k = 0; k < IPT; ++k)
            do_pair<SELFCHK>(cx0, cy0, cz0, s0, j0, ii[k], xi[k], yi[k], zi[k], mA[k], cA[k]);
        float cx1 = bcast_f(bx, l + 1), cy1 = bcast_f(by, l + 1), cz1 = bcast_f(bz, l + 1);
        unsigned s1 = __builtin_amdgcn_readlane(bs, l + 1);
#pragma unroll
        for (int k = 0; k < IPT; ++k)
            do_pair<SELFCHK>(cx1, cy1, cz1, s1, j0 + 1, ii[k], xi[k], yi[k], zi[k], mB[k], cB[k]);
    }
}

// ---------------------------------------------------------------------------
// pair kernel: thread owns IPT=4 atoms; wave loads its 64-atom j-chunk into
// registers once, then the hot loop is memory-free. Partials stored, no
// atomics. Block (0,0,0) zeroes the 8 output tail slots for finalize's
// atomicMax.
// ---------------------------------------------------------------------------
__global__ __launch_bounds__(BLK) void ns_pair_kernel(const float* __restrict__ coord,
                                                      const int* __restrict__ atype,
                                                      uint2* __restrict__ part,
                                                      float* __restrict__ out,
                                                      int nloc) {
    const int f = blockIdx.z;
    const int q = nloc / IPT;                     // 1024
    const int ib = blockIdx.y * BLK;              // in [0, q)
    const int jbase = blockIdx.x * (nloc / NJ);   // 64-aligned chunk base

    if (blockIdx.x == 0 && blockIdx.y == 0 && f == 0 && threadIdx.x < NFRAMES * NT)
        ((unsigned*)out)[(size_t)NFRAMES * nloc + threadIdx.x] = 0u;  // 0.0f bits

    const float* cf = coord + (size_t)f * nloc * 3;
    const int*   tf = atype + (size_t)f * nloc;

    // wave loads the j-chunk into per-lane registers (one-time, coalesced-ish)
    const int lane = threadIdx.x & 63;
    const int jl = jbase + lane;
    const float bx = cf[3 * jl], by = cf[3 * jl + 1], bz = cf[3 * jl + 2];
    const unsigned bs = 1u << (tf[jl] * 8);

    int ii[IPT];
    float xi[IPT], yi[IPT], zi[IPT];
    float mA[IPT], mB[IPT];
    unsigned cA[IPT], cB[IPT];
    bool ov = false;
#pragma unroll
    for (int k = 0; k < IPT; ++k) {
        const int base = ib + k * q;
        ii[k] = base + threadIdx.x;
        xi[k] = cf[3 * ii[k]];
        yi[k] = cf[3 * ii[k] + 1];
        zi[k] = cf[3 * ii[k] + 2];
        mA[k] = mB[k] = __builtin_inff();
        cA[k] = cB[k] = 0u;
        ov |= (jbase >= base) && (jbase < base + BLK);   // 64-chunk inside 256-range
    }

    if (ov)
        chunk_loop<true >(bx, by, bz, bs, jbase, ii, xi, yi, zi, mA, mB, cA, cB);
    else
        chunk_loop<false>(bx, by, bz, bs, jbase, ii, xi, yi, zi, mA, mB, cA, cB);

    const size_t pb = ((size_t)blockIdx.x * NFRAMES + f) * nloc;
#pragma unroll
    for (int k = 0; k < IPT; ++k)
        part[pb + ii[k]] = make_uint2(__float_as_uint(fminf(mA[k], mB[k])), cA[k] + cB[k]);
}

// ---------------------------------------------------------------------------
// finalize: per (f,i) reduce the NJ=64 partials; write min_rr2 to out; fold
// per-type count maxes into out tail via atomicMax on float bits.
// ---------------------------------------------------------------------------
__global__ __launch_bounds__(FBLK) void ns_finalize_kernel(const uint2* __restrict__ part,
                                                           float* __restrict__ out,
                                                           int nloc) {
    const int nbpf = nloc / FBLK;                 // 32 blocks per frame
    const int f = blockIdx.x / nbpf;
    const int i = (blockIdx.x % nbpf) * FBLK + threadIdx.x;

    float ma = __builtin_inff(), mb = __builtin_inff();
    unsigned cacc = 0u, cbacc = 0u;
#pragma unroll 8
    for (int jb = 0; jb < NJ; jb += 2) {
        uint2 va = part[((size_t)jb * NFRAMES + f) * nloc + i];
        uint2 vb = part[((size_t)(jb + 1) * NFRAMES + f) * nloc + i];
        ma = fminf(ma, __uint_as_float(va.x));
        mb = fminf(mb, __uint_as_float(vb.x));
        cacc += va.y;
        cbacc += vb.y;
    }
    out[(size_t)f * nloc + i] = fminf(ma, mb);
    const unsigned c = cacc + cbacc;

    int m0 = (int)(c & 255u);
    int m1 = (int)((c >> 8) & 255u);
    int m2 = (int)((c >> 16) & 255u);
    int m3 = (int)(c >> 24);
    for (int off = 32; off > 0; off >>= 1) {
        m0 = max(m0, __shfl_xor(m0, off, 64));
        m1 = max(m1, __shfl_xor(m1, off, 64));
        m2 = max(m2, __shfl_xor(m2, off, 64));
        m3 = max(m3, __shfl_xor(m3, off, 64));
    }
    __shared__ int red[FBLK / 64][NT];
    const int wid = threadIdx.x >> 6;
    if ((threadIdx.x & 63) == 0) {
        red[wid][0] = m0; red[wid][1] = m1; red[wid][2] = m2; red[wid][3] = m3;
    }
    __syncthreads();
    if (threadIdx.x < NT) {
        const int t = threadIdx.x;
        const int m = max(red[0][t], red[1][t]);
        atomicMax((unsigned*)out + (size_t)NFRAMES * nloc + f * NT + t,
                  __float_as_uint((float)m));
    }
}

extern "C" void kernel_launch(void* const* d_in, const int* in_sizes, int n_in,
                              void* d_out, int out_size, void* d_ws, size_t ws_size,
                              hipStream_t stream) {
    const float* coord = (const float*)d_in[0];
    const int*   atype = (const int*)d_in[1];
    const int nloc = in_sizes[1] / NFRAMES;

    float* out  = (float*)d_out;
    uint2* part = (uint2*)d_ws;                   // NJ * NFRAMES * nloc uint2

    dim3 grid(NJ, nloc / (BLK * IPT), NFRAMES);
    ns_pair_kernel<<<grid, dim3(BLK), 0, stream>>>(coord, atype, part, out, nloc);

    const int nbpf = nloc / FBLK;
    ns_finalize_kernel<<<NFRAMES * nbpf, FBLK, 0, stream>>>(part, out, nloc);
}